// Round 6
// baseline (687.988 us; speedup 1.0000x reference)
//
#include <hip/hip_runtime.h>
#include <math.h>

// ---------------------------------------------------------------------------
// Problem: B=2048, H=W=16, DICT=14, SE=8, CE=16, ESZ=512, NZ=512
// out = (2048,2048) f32.  All heavy math on MFMA via split-bf16:
//   tower1 / final path : 2-way split, 3 products  (~1.5e-5 rel)
//   tower2 / argmax path: 3-way split, 6 products  (~f32-equivalent)
// Round 6: GEMM B-operand read direct from global (L2-resident panels) ->
// LDS halved to A-only, occupancy 3->4+ blocks/CU; prep kernels fused;
// dispatches 13 -> 9.
// ---------------------------------------------------------------------------

typedef __attribute__((ext_vector_type(8))) __bf16 bf16x8;
typedef __attribute__((ext_vector_type(4))) float f32x4;
typedef __attribute__((ext_vector_type(8))) unsigned short ushort8;
typedef __attribute__((ext_vector_type(4))) unsigned short ushort4v;

static __device__ __forceinline__ unsigned short f2bf(float x) {
  union { float f; unsigned u; } v; v.f = x;
  return (unsigned short)(v.u >> 16);
}
static __device__ __forceinline__ float bf2f(unsigned short h) {
  union { float f; unsigned u; } v; v.u = ((unsigned)h) << 16;
  return v.f;
}
template<int NS>
static __device__ __forceinline__ void split3(float x, unsigned short* h) {
  unsigned short q0 = f2bf(x); h[0] = q0;
  float r1 = x - bf2f(q0);
  unsigned short q1 = f2bf(r1); h[1] = q1;
  if constexpr (NS == 3) h[2] = f2bf(r1 - bf2f(q1));
}
static __device__ __forceinline__ void gload_lds16(const void* g, void* l) {
  __builtin_amdgcn_global_load_lds(
      (const __attribute__((address_space(1))) unsigned int*)g,
      (__attribute__((address_space(3))) unsigned int*)l, 16, 0, 0);
}
static __device__ __forceinline__ bf16x8 gfrag(const unsigned short* p) {
  return __builtin_bit_cast(bf16x8, *reinterpret_cast<const ushort8*>(p));
}
#define MFMA16(a, b, c) __builtin_amdgcn_mfma_f32_16x16x32_bf16((a), (b), (c), 0, 0, 0)

template<int NS>
static __device__ __forceinline__ f32x4 mfma_prod(const bf16x8* a, const bf16x8* b, f32x4 c) {
  c = MFMA16(a[0], b[0], c);
  c = MFMA16(a[0], b[1], c);
  c = MFMA16(a[1], b[0], c);
  if constexpr (NS == 3) {
    c = MFMA16(a[1], b[1], c);
    c = MFMA16(a[0], b[2], c);
    c = MFMA16(a[2], b[0], c);
  }
  return c;
}
// swizzled ushort16-unit index for the [cell][16ch] conv act buffers
static __device__ __forceinline__ int conv_a16(int cell, int half) {
  return (cell * 2 + half) ^ ((cell >> 2) & 7);
}
// packed argmax key: monotone f32 bits in high 32, (511-col) low (first-occ ties)
static __device__ __forceinline__ unsigned long long score_key(float v, int col) {
  unsigned b = __float_as_uint(v);
  unsigned m = b ^ ((unsigned)((int)b >> 31) | 0x80000000u);
  return ((unsigned long long)m << 32) | (unsigned)(511 - col);
}
static __device__ __forceinline__ unsigned long long shfl_xor_u64(unsigned long long v, int m) {
  unsigned lo = __shfl_xor((unsigned)v, m, 64);
  unsigned hi = __shfl_xor((unsigned)(v >> 32), m, 64);
  return ((unsigned long long)hi << 32) | lo;
}

// ---------------------------------------------------------------------------
// K0: fully fused prep.
//  block 0:            table = se / max(||row||,1)
//  blocks 1..512:      zn row norm + 3-way split
//  blocks 513..1024:   zero epre (2048x512 f32)
//  blocks 1025..1032:  init zi keys to 0
//  blocks 1033..1230:  conv-weight pre-split/transpose (50688 elems)
//  blocks 1231..9422:  linear-weight splits (p1lw 2-way, p2lw 3-way)
// ---------------------------------------------------------------------------
__global__ __launch_bounds__(256) void prep_all_kernel(
    const float* __restrict__ se, float* __restrict__ tbl,
    const float* __restrict__ zv,
    unsigned short* __restrict__ zn0, unsigned short* __restrict__ zn1,
    unsigned short* __restrict__ zn2,
    float* __restrict__ epre, unsigned long long* __restrict__ zi,
    const float* __restrict__ ew,
    const float* __restrict__ p1c1w, const float* __restrict__ p1c2w,
    const float* __restrict__ p2c1w, const float* __restrict__ p2c2w,
    unsigned short* __restrict__ wt,
    const float* __restrict__ p1lw, const float* __restrict__ p2lw,
    unsigned short* __restrict__ w0, unsigned short* __restrict__ w1,
    unsigned short* __restrict__ u0, unsigned short* __restrict__ u1,
    unsigned short* __restrict__ u2)
{
  __shared__ float wsum[4];
  const int b = blockIdx.x, t = threadIdx.x;
  if (b == 0) {
    if (t < 112) {
      int r = t >> 3;
      float ss = 0.f;
      #pragma unroll
      for (int i = 0; i < 8; ++i) { float v = se[r * 8 + i]; ss += v * v; }
      float n = fmaxf(sqrtf(ss), 1.0f);
      tbl[t] = se[t] / n;
    }
  } else if (b <= 512) {
    int row = b - 1;
    size_t base = (size_t)row * 512 + t * 2;
    float2 v = *reinterpret_cast<const float2*>(zv + base);
    float ss = v.x * v.x + v.y * v.y;
    #pragma unroll
    for (int m = 32; m >= 1; m >>= 1) ss += __shfl_xor(ss, m, 64);
    int lane = t & 63, wid = t >> 6;
    if (lane == 0) wsum[wid] = ss;
    __syncthreads();
    float tot = wsum[0] + wsum[1] + wsum[2] + wsum[3];
    float inv = 1.0f / sqrtf(tot);
    float a = v.x * inv, c = v.y * inv;
    unsigned short ha[3], hc[3];
    split3<3>(a, ha); split3<3>(c, hc);
    zn0[base] = ha[0]; zn0[base + 1] = hc[0];
    zn1[base] = ha[1]; zn1[base + 1] = hc[1];
    zn2[base] = ha[2]; zn2[base + 1] = hc[2];
  } else if (b <= 1024) {
    f32x4 z4 = {0.f, 0.f, 0.f, 0.f};
    size_t o = ((size_t)(b - 513) * 256 + t) * 8;
    *reinterpret_cast<f32x4*>(epre + o) = z4;
    *reinterpret_cast<f32x4*>(epre + o + 4) = z4;
  } else if (b <= 1032) {
    int i = (b - 1025) * 256 + t;
    if (i < 2048) zi[i] = 0ull;
  } else if (b <= 1230) {
    int gi = (b - 1033) * 256 + t;
    if (gi >= 50688) return;
    const float* src; int off, NSs, OC, mode;
    if (gi < 4608)       { src = ew;    off = 0;     NSs = 3; OC = 16; mode = 0; }
    else if (gi < 12288) { src = p1c1w; off = 4608;  NSs = 5; OC = 16; mode = 1; }
    else if (gi < 27648) { src = p1c2w; off = 12288; NSs = 5; OC = 32; mode = 1; }
    else if (gi < 35328) { src = p2c1w; off = 27648; NSs = 5; OC = 16; mode = 1; }
    else                 { src = p2c2w; off = 35328; NSs = 5; OC = 32; mode = 1; }
    int i = gi - off;
    int ic = i & 7;
    int r = i >> 3;
    int oc = r % OC; r /= OC;
    int kc = r & 3; r >>= 2;
    int s = r % NSs;
    int sp = r / NSs;
    int tap, icf, IC;
    if (mode == 0) { tap = s * 4 + kc; icf = ic; IC = 8; }
    else           { tap = s * 2 + (kc >> 1); icf = (kc & 1) * 8 + ic; IC = 16; }
    float w = 0.f;
    if (tap < 9) {
      int ky = tap / 3, kx = tap - ky * 3;
      w = src[((oc * IC + icf) * 3 + ky) * 3 + kx];
    }
    unsigned short h[3];
    split3<3>(w, h);
    wt[gi] = h[sp];
  } else {
    int blk = b - 1231;
    if (blk < 4096) {
      size_t i = ((size_t)blk * 256 + t) * 4;
      f32x4 v = *reinterpret_cast<const f32x4*>(p1lw + i);
      ushort4v a, b2;
      #pragma unroll
      for (int j = 0; j < 4; ++j) {
        unsigned short h[3];
        split3<2>(v[j], h);
        a[j] = h[0]; b2[j] = h[1];
      }
      *reinterpret_cast<ushort4v*>(w0 + i) = a;
      *reinterpret_cast<ushort4v*>(w1 + i) = b2;
    } else {
      size_t i = ((size_t)(blk - 4096) * 256 + t) * 4;
      f32x4 v = *reinterpret_cast<const f32x4*>(p2lw + i);
      ushort4v a, b2, c;
      #pragma unroll
      for (int j = 0; j < 4; ++j) {
        unsigned short h[3];
        split3<3>(v[j], h);
        a[j] = h[0]; b2[j] = h[1]; c[j] = h[2];
      }
      *reinterpret_cast<ushort4v*>(u0 + i) = a;
      *reinterpret_cast<ushort4v*>(u1 + i) = b2;
      *reinterpret_cast<ushort4v*>(u2 + i) = c;
    }
  }
}

// ---------------------------------------------------------------------------
// K1: row-normalize (rows x 512) + bias, emit 2-3 bf16 splits; optionally
// re-zero the source buffer for atomic reuse.
// ---------------------------------------------------------------------------
__global__ __launch_bounds__(256) void reduce_norm_kernel(
    const float* __restrict__ pre, const float* __restrict__ bias, float eps,
    unsigned short* __restrict__ o0, unsigned short* __restrict__ o1,
    unsigned short* __restrict__ o2, float* __restrict__ zero_dst)
{
  int row = blockIdx.x, t = threadIdx.x;
  size_t base = (size_t)row * 512 + t * 2;
  float2 v = *reinterpret_cast<const float2*>(pre + base);
  float ax = v.x + bias[t * 2], ay = v.y + bias[t * 2 + 1];
  float ss = ax * ax + ay * ay;
  #pragma unroll
  for (int m = 32; m >= 1; m >>= 1) ss += __shfl_xor(ss, m, 64);
  __shared__ float wsum[4];
  int lane = t & 63, wid = t >> 6;
  if (lane == 0) wsum[wid] = ss;
  __syncthreads();
  float tot = wsum[0] + wsum[1] + wsum[2] + wsum[3];
  float inv = 1.0f / (sqrtf(tot) + eps);
  float a = ax * inv, b2 = ay * inv;
  unsigned short ha[3], hb[3];
  split3<3>(a, ha); split3<3>(b2, hb);
  o0[base] = ha[0]; o0[base + 1] = hb[0];
  o1[base] = ha[1]; o1[base + 1] = hb[1];
  if (o2) { o2[base] = ha[2]; o2[base + 1] = hb[2]; }
  if (zero_dst) {
    float2 z = {0.f, 0.f};
    *reinterpret_cast<float2*>(zero_dst + base) = z;
  }
}

// ---------------------------------------------------------------------------
// K3: fused MFMA tower (verified rounds 3-5).
// ---------------------------------------------------------------------------
template<int NS>
__global__ __launch_bounds__(256) void tower_mfma_kernel(
    const int* __restrict__ sIdx, const int* __restrict__ spIdx,
    const float* __restrict__ tblf,
    const unsigned short* __restrict__ wtE,
    const unsigned short* __restrict__ wt1,
    const unsigned short* __restrict__ wt2,
    const float* __restrict__ eb, const float* __restrict__ c1b,
    const float* __restrict__ c2b,
    unsigned short* __restrict__ a0, unsigned short* __restrict__ a1,
    unsigned short* __restrict__ a2, int delta)
{
  __shared__ float tbl[112];
  __shared__ ushort8 G[NS][324];      // [cell][8ch]
  __shared__ ushort8 Abuf[NS][648];   // [cell][16ch] swizzled
  __shared__ ushort8 Bbuf[NS][648];

  const int b = blockIdx.x, t = threadIdx.x;
  const int lane = t & 63, wv = t >> 6;
  const int fr = lane & 15, kc = lane >> 4;

  if (t < 112) tbl[t] = tblf[t];
  // zero only the 68-cell halo ring (interiors are fully overwritten)
  if (t < 68) {
    int c;
    if (t < 18)      c = t;
    else if (t < 36) c = 306 + (t - 18);
    else if (t < 52) c = 18 * (t - 35);
    else             c = 18 * (t - 51) + 17;
    ushort8 z8 = {0, 0, 0, 0, 0, 0, 0, 0};
    #pragma unroll
    for (int sp = 0; sp < NS; ++sp) {
      G[sp][c] = z8;
      ((ushort8*)&Abuf[sp][0])[conv_a16(c, 0)] = z8;
      ((ushort8*)&Abuf[sp][0])[conv_a16(c, 1)] = z8;
      ((ushort8*)&Bbuf[sp][0])[conv_a16(c, 0)] = z8;
      ((ushort8*)&Bbuf[sp][0])[conv_a16(c, 1)] = z8;
    }
  }
  __syncthreads();

  // ---- gather + split -> G ----
  {
    const int y = t >> 4, x = t & 15;
    const int cell = (y + 1) * 18 + (x + 1);
    int sv = sIdx[(size_t)b * 256 + t];
    float v[8];
    if (delta) {
      int spv = spIdx[(size_t)b * 256 + t];
      #pragma unroll
      for (int c = 0; c < 8; ++c) v[c] = tbl[spv * 8 + c] - tbl[sv * 8 + c];
    } else {
      #pragma unroll
      for (int c = 0; c < 8; ++c) v[c] = tbl[sv * 8 + c];
    }
    ushort8 h0, h1, h2;
    #pragma unroll
    for (int c = 0; c < 8; ++c) {
      unsigned short q[3];
      split3<NS>(v[c], q);
      h0[c] = q[0]; h1[c] = q[1];
      if constexpr (NS == 3) h2[c] = q[2];
    }
    G[0][cell] = h0; G[1][cell] = h1;
    if constexpr (NS == 3) G[2][cell] = h2;
  }
  __syncthreads();

  // ---- embed conv 8->16 (no relu; bias only for tower1) -> Abuf ----
  {
    float bias = 0.f;
    if (!delta) bias = eb[fr];
    f32x4 acc[4];
    #pragma unroll
    for (int j = 0; j < 4; ++j) acc[j] = (f32x4)0.f;
    #pragma unroll
    for (int s = 0; s < 3; ++s) {
      bf16x8 bw[NS];
      #pragma unroll
      for (int sp = 0; sp < NS; ++sp)
        bw[sp] = __builtin_bit_cast(bf16x8, *reinterpret_cast<const ushort8*>(
            wtE + (size_t)(((sp * 3 + s) * 4 + kc) * 16 + fr) * 8));
      int tap = s * 4 + kc; if (tap > 8) tap = 8;
      const int dy = tap / 3, dx = tap - dy * 3;
      const int cb = dy * 18 + fr + dx;
      #pragma unroll
      for (int j = 0; j < 4; ++j) {
        const int cell = cb + (wv * 4 + j) * 18;
        bf16x8 av[NS];
        #pragma unroll
        for (int sp = 0; sp < NS; ++sp)
          av[sp] = __builtin_bit_cast(bf16x8, G[sp][cell]);
        acc[j] = mfma_prod<NS>(av, bw, acc[j]);
      }
    }
    #pragma unroll
    for (int j = 0; j < 4; ++j) {
      const int y = wv * 4 + j;
      #pragma unroll
      for (int q = 0; q < 4; ++q) {
        const int x = kc * 4 + q;
        const int cell = (y + 1) * 18 + (x + 1);
        const int a16 = conv_a16(cell, fr >> 3);
        unsigned short hh[3];
        split3<NS>(acc[j][q] + bias, hh);
        #pragma unroll
        for (int sp = 0; sp < NS; ++sp)
          ((unsigned short*)&Abuf[sp][0])[a16 * 8 + (fr & 7)] = hh[sp];
      }
    }
  }
  __syncthreads();

  // ---- conv1 16->16, relu -> Bbuf ----
  {
    const float bias = c1b[fr];
    f32x4 acc[4];
    #pragma unroll
    for (int j = 0; j < 4; ++j) acc[j] = (f32x4)0.f;
    #pragma unroll
    for (int s = 0; s < 5; ++s) {
      bf16x8 bw[NS];
      #pragma unroll
      for (int sp = 0; sp < NS; ++sp)
        bw[sp] = __builtin_bit_cast(bf16x8, *reinterpret_cast<const ushort8*>(
            wt1 + (size_t)(((sp * 5 + s) * 4 + kc) * 16 + fr) * 8));
      int tap = s * 2 + (kc >> 1); if (tap > 8) tap = 8;
      const int dy = tap / 3, dx = tap - dy * 3;
      const int half = kc & 1;
      const int cb = dy * 18 + fr + dx;
      #pragma unroll
      for (int j = 0; j < 4; ++j) {
        const int cell = cb + (wv * 4 + j) * 18;
        const int a16 = conv_a16(cell, half);
        bf16x8 av[NS];
        #pragma unroll
        for (int sp = 0; sp < NS; ++sp)
          av[sp] = __builtin_bit_cast(bf16x8, *reinterpret_cast<const ushort8*>(
              (const unsigned short*)&Abuf[sp][0] + a16 * 8));
        acc[j] = mfma_prod<NS>(av, bw, acc[j]);
      }
    }
    #pragma unroll
    for (int j = 0; j < 4; ++j) {
      const int y = wv * 4 + j;
      #pragma unroll
      for (int q = 0; q < 4; ++q) {
        const int x = kc * 4 + q;
        const int cell = (y + 1) * 18 + (x + 1);
        const int a16 = conv_a16(cell, fr >> 3);
        unsigned short hh[3];
        split3<NS>(fmaxf(acc[j][q] + bias, 0.f), hh);
        #pragma unroll
        for (int sp = 0; sp < NS; ++sp)
          ((unsigned short*)&Bbuf[sp][0])[a16 * 8 + (fr & 7)] = hh[sp];
      }
    }
  }
  __syncthreads();

  // ---- conv2 16->32, relu -> global act splits ----
  {
    const float bias0 = c2b[fr], bias1 = c2b[16 + fr];
    f32x4 acc0[4], acc1[4];
    #pragma unroll
    for (int j = 0; j < 4; ++j) { acc0[j] = (f32x4)0.f; acc1[j] = (f32x4)0.f; }
    #pragma unroll
    for (int s = 0; s < 5; ++s) {
      bf16x8 bw0[NS], bw1[NS];
      #pragma unroll
      for (int sp = 0; sp < NS; ++sp) {
        size_t base = (size_t)(((sp * 5 + s) * 4 + kc) * 32) * 8;
        bw0[sp] = __builtin_bit_cast(bf16x8,
            *reinterpret_cast<const ushort8*>(wt2 + base + (size_t)fr * 8));
        bw1[sp] = __builtin_bit_cast(bf16x8,
            *reinterpret_cast<const ushort8*>(wt2 + base + (size_t)(16 + fr) * 8));
      }
      int tap = s * 2 + (kc >> 1); if (tap > 8) tap = 8;
      const int dy = tap / 3, dx = tap - dy * 3;
      const int half = kc & 1;
      const int cb = dy * 18 + fr + dx;
      #pragma unroll
      for (int j = 0; j < 4; ++j) {
        const int cell = cb + (wv * 4 + j) * 18;
        const int a16 = conv_a16(cell, half);
        bf16x8 av[NS];
        #pragma unroll
        for (int sp = 0; sp < NS; ++sp)
          av[sp] = __builtin_bit_cast(bf16x8, *reinterpret_cast<const ushort8*>(
              (const unsigned short*)&Bbuf[sp][0] + a16 * 8));
        acc0[j] = mfma_prod<NS>(av, bw0, acc0[j]);
        acc1[j] = mfma_prod<NS>(av, bw1, acc1[j]);
      }
    }
    #pragma unroll
    for (int j = 0; j < 4; ++j) {
      const int y = wv * 4 + j;
      ushort4v g0[2], g1[2], g2[2];
      #pragma unroll
      for (int q = 0; q < 4; ++q) {
        unsigned short hh[3];
        split3<NS>(fmaxf(acc0[j][q] + bias0, 0.f), hh);
        g0[0][q] = hh[0]; g1[0][q] = hh[1]; if constexpr (NS == 3) g2[0][q] = hh[2];
        split3<NS>(fmaxf(acc1[j][q] + bias1, 0.f), hh);
        g0[1][q] = hh[0]; g1[1][q] = hh[1]; if constexpr (NS == 3) g2[1][q] = hh[2];
      }
      size_t base0 = (size_t)b * 8192 + (size_t)fr * 256 + y * 16 + kc * 4;
      size_t base1 = base0 + 16 * 256;
      *reinterpret_cast<ushort4v*>(a0 + base0) = g0[0];
      *reinterpret_cast<ushort4v*>(a0 + base1) = g0[1];
      *reinterpret_cast<ushort4v*>(a1 + base0) = g1[0];
      *reinterpret_cast<ushort4v*>(a1 + base1) = g1[1];
      if constexpr (NS == 3) {
        *reinterpret_cast<ushort4v*>(a2 + base0) = g2[0];
        *reinterpret_cast<ushort4v*>(a2 + base1) = g2[1];
      }
    }
  }
}

// ---------------------------------------------------------------------------
// K4: split-bf16 MFMA GEMM, C = A @ B^T.  128x128 tile, BK=32, 4 waves.
//   A: pre-split NS tiles via global_load_lds (swizzled LDS, A-only LDS).
//   B: read DIRECT from global per product group (panels are L2-resident);
//      fragment addr = row*K + k0 + kc*8 (16B/lane) — identical values to
//      the former LDS path.
//   EPI: 0 = atomicAdd into C (K-split reduction)
//        2 = final write: gather B row from packed zi keys, * exp(scale)
//        3 = score-argmax: per-row packed-key atomicMax into zout (no C)
// ---------------------------------------------------------------------------
template<int NS, int EPI>
__global__ __launch_bounds__(256, 4) void mfma_gemm_kernel(
    const unsigned short* __restrict__ A0, const unsigned short* __restrict__ A1,
    const unsigned short* __restrict__ A2,
    const unsigned short* __restrict__ B0, const unsigned short* __restrict__ B1,
    const unsigned short* __restrict__ B2,
    const unsigned long long* __restrict__ gkey,
    unsigned long long* __restrict__ zout,
    const float* __restrict__ scale_p,
    float* __restrict__ C, int M, int N, int K, int Ksub)
{
  __shared__ unsigned short ldsA[NS][4096];

  const int t = threadIdx.x;
  const int lane = t & 63, wv = t >> 6;
  const int m0 = blockIdx.x * 128, n0 = blockIdx.y * 128;
  const long kbase = (long)blockIdx.z * Ksub;
  const int NT = Ksub >> 5;

  const int st_row = lane >> 2;
  const int st_cb = (lane & 3) * 16;
  int srow[2];
  #pragma unroll
  for (int r = 0; r < 2; ++r) srow[r] = (wv + 4 * r) * 16 + st_row;

  const int wr = wv >> 1, wc = wv & 1;
  const int fr = lane & 15, kc = lane >> 4;

  // B row index per n-fragment (per-lane; gather for EPI==2)
  size_t brow[4];
  #pragma unroll
  for (int ni = 0; ni < 4; ++ni) {
    int col = n0 + wc * 64 + ni * 16 + fr;
    long g = col;
    if constexpr (EPI == 2) g = 511 - (long)(unsigned)(gkey[col] & 0xFFFFFFFFull);
    brow[ni] = (size_t)g * K;
  }

  f32x4 acc[4][4];
  #pragma unroll
  for (int mi = 0; mi < 4; ++mi)
    #pragma unroll
    for (int ni = 0; ni < 4; ++ni) acc[mi][ni] = (f32x4)0.f;

  const unsigned short* Asp[3] = {A0, A1, A2};

  for (int kt = 0; kt < NT; ++kt) {
    const long k0 = kbase + (long)kt * 32;
    // ---- A staging (async DMA, swizzled dest via pre-swizzled source) ----
    #pragma unroll
    for (int sp = 0; sp < NS; ++sp)
      #pragma unroll
      for (int r = 0; r < 2; ++r) {
        int row = srow[r];
        int c = st_cb ^ (((row >> 1) & 3) << 4);
        gload_lds16(Asp[sp] + (size_t)(m0 + row) * K + k0 + (c >> 1),
                    &ldsA[sp][(wv + 4 * r) * 512]);
      }
    __syncthreads();

    // ---- A fragments from LDS ----
    bf16x8 af[NS][4];
    #pragma unroll
    for (int sp = 0; sp < NS; ++sp)
      #pragma unroll
      for (int mi = 0; mi < 4; ++mi) {
        int row = wr * 64 + mi * 16 + fr;
        int cb = (kc * 16) ^ (((row >> 1) & 3) << 4);
        af[sp][mi] = __builtin_bit_cast(bf16x8,
            *reinterpret_cast<const ushort8*>(&ldsA[sp][row * 32 + (cb >> 1)]));
      }

    // ---- B fragments direct from global, JIT per split group ----
    const long koff = k0 + kc * 8;
    bf16x8 bb[4];
    // group B0: products (0,0),(1,0)[,(2,0)]
    #pragma unroll
    for (int ni = 0; ni < 4; ++ni) bb[ni] = gfrag(B0 + brow[ni] + koff);
    #pragma unroll
    for (int mi = 0; mi < 4; ++mi)
      #pragma unroll
      for (int ni = 0; ni < 4; ++ni)
        acc[mi][ni] = MFMA16(af[0][mi], bb[ni], acc[mi][ni]);
    #pragma unroll
    for (int mi = 0; mi < 4; ++mi)
      #pragma unroll
      for (int ni = 0; ni < 4; ++ni)
        acc[mi][ni] = MFMA16(af[1][mi], bb[ni], acc[mi][ni]);
    if constexpr (NS == 3) {
      #pragma unroll
      for (int mi = 0; mi < 4; ++mi)
        #pragma unroll
        for (int ni = 0; ni < 4; ++ni)
          acc[mi][ni] = MFMA16(af[2][mi], bb[ni], acc[mi][ni]);
    }
    // group B1: products (0,1)[,(1,1)]
    #pragma unroll
    for (int ni = 0; ni < 4; ++ni) bb[ni] = gfrag(B1 + brow[ni] + koff);
    #pragma unroll
    for (int mi = 0; mi < 4; ++mi)
      #pragma unroll
      for (int ni = 0; ni < 4; ++ni)
        acc[mi][ni] = MFMA16(af[0][mi], bb[ni], acc[mi][ni]);
    if constexpr (NS == 3) {
      #pragma unroll
      for (int mi = 0; mi < 4; ++mi)
        #pragma unroll
        for (int ni = 0; ni < 4; ++ni)
          acc[mi][ni] = MFMA16(af[1][mi], bb[ni], acc[mi][ni]);
      // group B2: product (0,2)
      #pragma unroll
      for (int ni = 0; ni < 4; ++ni) bb[ni] = gfrag(B2 + brow[ni] + koff);
      #pragma unroll
      for (int mi = 0; mi < 4; ++mi)
        #pragma unroll
        for (int ni = 0; ni < 4; ++ni)
          acc[mi][ni] = MFMA16(af[0][mi], bb[ni], acc[mi][ni]);
    }
    __syncthreads();
  }

  // epilogue: C/D layout col=lane&15, row=(lane>>4)*4+q
  if constexpr (EPI == 0) {
    #pragma unroll
    for (int mi = 0; mi < 4; ++mi)
      #pragma unroll
      for (int ni = 0; ni < 4; ++ni) {
        int col = n0 + wc * 64 + ni * 16 + fr;
        #pragma unroll
        for (int q = 0; q < 4; ++q) {
          int row = m0 + wr * 64 + mi * 16 + kc * 4 + q;
          atomicAdd(&C[(size_t)row * N + col], acc[mi][ni][q]);
        }
      }
  } else if constexpr (EPI == 2) {
    float scl = expf(scale_p[0]);
    #pragma unroll
    for (int mi = 0; mi < 4; ++mi)
      #pragma unroll
      for (int ni = 0; ni < 4; ++ni) {
        int col = n0 + wc * 64 + ni * 16 + fr;
        #pragma unroll
        for (int q = 0; q < 4; ++q) {
          int row = m0 + wr * 64 + mi * 16 + kc * 4 + q;
          C[(size_t)row * N + col] = acc[mi][ni][q] * scl;
        }
      }
  } else {  // EPI == 3: fused argmax (full K per block — no k-split!)
    #pragma unroll
    for (int mi = 0; mi < 4; ++mi)
      #pragma unroll
      for (int q = 0; q < 4; ++q) {
        int row = m0 + wr * 64 + mi * 16 + kc * 4 + q;
        unsigned long long best = 0ull;
        #pragma unroll
        for (int ni = 0; ni < 4; ++ni) {
          int col = n0 + wc * 64 + ni * 16 + fr;
          unsigned long long k2 = score_key(acc[mi][ni][q], col);
          best = (k2 > best) ? k2 : best;
        }
        #pragma unroll
        for (int m2 = 1; m2 < 16; m2 <<= 1) {
          unsigned long long o = shfl_xor_u64(best, m2);
          best = (o > best) ? o : best;
        }
        if (fr == 0) atomicMax(zout + row, best);
      }
  }
}

// ---------------------------------------------------------------------------
// launch
// ---------------------------------------------------------------------------
extern "C" void kernel_launch(void* const* d_in, const int* in_sizes, int n_in,
                              void* d_out, int out_size, void* d_ws, size_t ws_size,
                              hipStream_t stream)
{
  const int*   s      = (const int*)  d_in[0];
  const int*   sprime = (const int*)  d_in[1];
  const float* se     = (const float*)d_in[2];
  const float* ew     = (const float*)d_in[3];
  const float* eb     = (const float*)d_in[4];
  const float* p1c1w  = (const float*)d_in[5];
  const float* p1c1b  = (const float*)d_in[6];
  const float* p1c2w  = (const float*)d_in[7];
  const float* p1c2b  = (const float*)d_in[8];
  const float* p1lw   = (const float*)d_in[9];
  const float* p1lb   = (const float*)d_in[10];
  const float* p2c1w  = (const float*)d_in[11];
  const float* p2c1b  = (const float*)d_in[12];
  const float* p2c2w  = (const float*)d_in[13];
  const float* p2c2b  = (const float*)d_in[14];
  const float* p2lw   = (const float*)d_in[15];
  const float* p2lb   = (const float*)d_in[16];
  const float* zv     = (const float*)d_in[17];
  const float* scale  = (const float*)d_in[18];
  float* out = (float*)d_out;

  // ---- workspace (peak ~136 MB) ----
  char* w = (char*)d_ws;
  size_t off = 0;
  auto alloc = [&](size_t bytes) -> char* {
    char* p = w + off;
    off += (bytes + 255) & ~(size_t)255;
    return p;
  };
  float* tblf = (float*)alloc(112 * 4);
  unsigned short* zn0 = (unsigned short*)alloc((size_t)512 * 512 * 2);
  unsigned short* zn1 = (unsigned short*)alloc((size_t)512 * 512 * 2);
  unsigned short* zn2 = (unsigned short*)alloc((size_t)512 * 512 * 2);
  unsigned short* e10 = (unsigned short*)alloc((size_t)2048 * 512 * 2);
  unsigned short* e11 = (unsigned short*)alloc((size_t)2048 * 512 * 2);
  unsigned short* e20 = (unsigned short*)alloc((size_t)2048 * 512 * 2);
  unsigned short* e21 = (unsigned short*)alloc((size_t)2048 * 512 * 2);
  unsigned short* e22 = (unsigned short*)alloc((size_t)2048 * 512 * 2);
  float* epre = (float*)alloc((size_t)2048 * 512 * 4);
  unsigned long long* zi = (unsigned long long*)alloc(2048 * 8);
  unsigned short* wt = (unsigned short*)alloc((size_t)50688 * 2);
  unsigned short* act0 = (unsigned short*)alloc((size_t)2048 * 8192 * 2);
  unsigned short* act1 = (unsigned short*)alloc((size_t)2048 * 8192 * 2);
  unsigned short* act2 = (unsigned short*)alloc((size_t)2048 * 8192 * 2);
  unsigned short* u0 = (unsigned short*)alloc((size_t)512 * 8192 * 2);
  unsigned short* u1 = (unsigned short*)alloc((size_t)512 * 8192 * 2);
  unsigned short* u2 = (unsigned short*)alloc((size_t)512 * 8192 * 2);
  // p1 linear-weight splits alias act2 (32 MB >= 2 x 8 MB): tower1 is NS=2
  // (never writes act2); tower2 overwrites act2 only after GEMM1 completes.
  unsigned short* w0 = act2;
  unsigned short* w1 = act2 + (size_t)512 * 8192;

  unsigned short* wtE  = wt;
  unsigned short* wt1a = wt + 4608;
  unsigned short* wt2a = wt + 12288;
  unsigned short* wt1b = wt + 27648;
  unsigned short* wt2b = wt + 35328;

  // ---- one fused prep dispatch ----
  prep_all_kernel<<<9423, 256, 0, stream>>>(
      se, tblf, zv, zn0, zn1, zn2, epre, zi,
      ew, p1c1w, p1c2w, p2c1w, p2c2w, wt,
      p1lw, p2lw, w0, w1, u0, u1, u2);

  // ---- tower 1 (2-way split) -> act0/1 ; linear (KSPLIT=8) ; norm ----
  tower_mfma_kernel<2><<<2048, 256, 0, stream>>>(
      s, sprime, tblf, wtE, wt1a, wt2a, eb, p1c1b, p1c2b, act0, act1, act2, 0);
  mfma_gemm_kernel<2, 0><<<dim3(16, 4, 8), 256, 0, stream>>>(
      act0, act1, nullptr, w0, w1, nullptr, nullptr, nullptr,
      nullptr, epre, 2048, 512, 8192, 1024);
  reduce_norm_kernel<<<2048, 256, 0, stream>>>(epre, p1lb, 1e-4f,
                                               e10, e11, nullptr, epre);

  // ---- tower 2 (3-way split, argmax-critical) -> act0/1/2 ; linear ; norm --
  tower_mfma_kernel<3><<<2048, 256, 0, stream>>>(
      s, sprime, tblf, wtE, wt1b, wt2b, eb, p2c1b, p2c2b, act0, act1, act2, 1);
  mfma_gemm_kernel<3, 0><<<dim3(16, 4, 8), 256, 0, stream>>>(
      act0, act1, act2, u0, u1, u2, nullptr, nullptr,
      nullptr, epre, 2048, 512, 8192, 1024);
  reduce_norm_kernel<<<2048, 256, 0, stream>>>(epre, p2lb, 1e-4f,
                                               e20, e21, e22, nullptr);

  // ---- fused score+argmax (full-K blocks) -> final gathered GEMM ----
  mfma_gemm_kernel<3, 3><<<dim3(16, 4, 1), 256, 0, stream>>>(
      e20, e21, e22, zn0, zn1, zn2, nullptr, zi, nullptr,
      nullptr, 2048, 512, 512, 512);
  mfma_gemm_kernel<2, 2><<<dim3(16, 16, 1), 256, 0, stream>>>(
      e10, e11, nullptr, zn0, zn1, nullptr, zi, nullptr, scale,
      out, 2048, 2048, 512, 512);
}

// Round 7
// 446.781 us; speedup vs baseline: 1.5399x; 1.5399x over previous
//
#include <hip/hip_runtime.h>
#include <math.h>

// ---------------------------------------------------------------------------
// Problem: B=2048, H=W=16, DICT=14, SE=8, CE=16, ESZ=512, NZ=512
// out = (2048,2048) f32.  All heavy math on MFMA via split-bf16:
//   tower1 / final path : 2-way split, 3 products  (~1.5e-5 rel)
//   tower2 / argmax path: 3-way split, 6 products  (~f32-equivalent)
// Round 7: revert round-6 direct-global B (L2 thrash: FETCH 373MB, WRITE
// 505MB). Round-5 LDS staging + single-buffer pipeline reorder:
// read-frags -> barrier -> stage(kt+1) -> MFMA, so next-tile load latency
// hides under the MFMA block instead of serializing.
// ---------------------------------------------------------------------------

typedef __attribute__((ext_vector_type(8))) __bf16 bf16x8;
typedef __attribute__((ext_vector_type(4))) float f32x4;
typedef __attribute__((ext_vector_type(8))) unsigned short ushort8;
typedef __attribute__((ext_vector_type(4))) unsigned short ushort4v;

static __device__ __forceinline__ unsigned short f2bf(float x) {
  union { float f; unsigned u; } v; v.f = x;
  return (unsigned short)(v.u >> 16);
}
static __device__ __forceinline__ float bf2f(unsigned short h) {
  union { float f; unsigned u; } v; v.u = ((unsigned)h) << 16;
  return v.f;
}
template<int NS>
static __device__ __forceinline__ void split3(float x, unsigned short* h) {
  unsigned short q0 = f2bf(x); h[0] = q0;
  float r1 = x - bf2f(q0);
  unsigned short q1 = f2bf(r1); h[1] = q1;
  if constexpr (NS == 3) h[2] = f2bf(r1 - bf2f(q1));
}
static __device__ __forceinline__ void gload_lds16(const void* g, void* l) {
  __builtin_amdgcn_global_load_lds(
      (const __attribute__((address_space(1))) unsigned int*)g,
      (__attribute__((address_space(3))) unsigned int*)l, 16, 0, 0);
}
#define MFMA16(a, b, c) __builtin_amdgcn_mfma_f32_16x16x32_bf16((a), (b), (c), 0, 0, 0)

template<int NS>
static __device__ __forceinline__ f32x4 mfma_prod(const bf16x8* a, const bf16x8* b, f32x4 c) {
  c = MFMA16(a[0], b[0], c);
  c = MFMA16(a[0], b[1], c);
  c = MFMA16(a[1], b[0], c);
  if constexpr (NS == 3) {
    c = MFMA16(a[1], b[1], c);
    c = MFMA16(a[0], b[2], c);
    c = MFMA16(a[2], b[0], c);
  }
  return c;
}
// swizzled ushort16-unit index for the [cell][16ch] conv act buffers
static __device__ __forceinline__ int conv_a16(int cell, int half) {
  return (cell * 2 + half) ^ ((cell >> 2) & 7);
}
// packed argmax key: monotone f32 bits in high 32, (511-col) low (first-occ ties)
static __device__ __forceinline__ unsigned long long score_key(float v, int col) {
  unsigned b = __float_as_uint(v);
  unsigned m = b ^ ((unsigned)((int)b >> 31) | 0x80000000u);
  return ((unsigned long long)m << 32) | (unsigned)(511 - col);
}
static __device__ __forceinline__ unsigned long long shfl_xor_u64(unsigned long long v, int m) {
  unsigned lo = __shfl_xor((unsigned)v, m, 64);
  unsigned hi = __shfl_xor((unsigned)(v >> 32), m, 64);
  return ((unsigned long long)hi << 32) | lo;
}

// ---------------------------------------------------------------------------
// K0: fully fused prep (verified round 6).
//  block 0:            table = se / max(||row||,1)
//  blocks 1..512:      zn row norm + 3-way split
//  blocks 513..1024:   zero epre (2048x512 f32)
//  blocks 1025..1032:  init zi keys to 0
//  blocks 1033..1230:  conv-weight pre-split/transpose (50688 elems)
//  blocks 1231..9422:  linear-weight splits (p1lw 2-way, p2lw 3-way)
// ---------------------------------------------------------------------------
__global__ __launch_bounds__(256) void prep_all_kernel(
    const float* __restrict__ se, float* __restrict__ tbl,
    const float* __restrict__ zv,
    unsigned short* __restrict__ zn0, unsigned short* __restrict__ zn1,
    unsigned short* __restrict__ zn2,
    float* __restrict__ epre, unsigned long long* __restrict__ zi,
    const float* __restrict__ ew,
    const float* __restrict__ p1c1w, const float* __restrict__ p1c2w,
    const float* __restrict__ p2c1w, const float* __restrict__ p2c2w,
    unsigned short* __restrict__ wt,
    const float* __restrict__ p1lw, const float* __restrict__ p2lw,
    unsigned short* __restrict__ w0, unsigned short* __restrict__ w1,
    unsigned short* __restrict__ u0, unsigned short* __restrict__ u1,
    unsigned short* __restrict__ u2)
{
  __shared__ float wsum[4];
  const int b = blockIdx.x, t = threadIdx.x;
  if (b == 0) {
    if (t < 112) {
      int r = t >> 3;
      float ss = 0.f;
      #pragma unroll
      for (int i = 0; i < 8; ++i) { float v = se[r * 8 + i]; ss += v * v; }
      float n = fmaxf(sqrtf(ss), 1.0f);
      tbl[t] = se[t] / n;
    }
  } else if (b <= 512) {
    int row = b - 1;
    size_t base = (size_t)row * 512 + t * 2;
    float2 v = *reinterpret_cast<const float2*>(zv + base);
    float ss = v.x * v.x + v.y * v.y;
    #pragma unroll
    for (int m = 32; m >= 1; m >>= 1) ss += __shfl_xor(ss, m, 64);
    int lane = t & 63, wid = t >> 6;
    if (lane == 0) wsum[wid] = ss;
    __syncthreads();
    float tot = wsum[0] + wsum[1] + wsum[2] + wsum[3];
    float inv = 1.0f / sqrtf(tot);
    float a = v.x * inv, c = v.y * inv;
    unsigned short ha[3], hc[3];
    split3<3>(a, ha); split3<3>(c, hc);
    zn0[base] = ha[0]; zn0[base + 1] = hc[0];
    zn1[base] = ha[1]; zn1[base + 1] = hc[1];
    zn2[base] = ha[2]; zn2[base + 1] = hc[2];
  } else if (b <= 1024) {
    f32x4 z4 = {0.f, 0.f, 0.f, 0.f};
    size_t o = ((size_t)(b - 513) * 256 + t) * 8;
    *reinterpret_cast<f32x4*>(epre + o) = z4;
    *reinterpret_cast<f32x4*>(epre + o + 4) = z4;
  } else if (b <= 1032) {
    int i = (b - 1025) * 256 + t;
    if (i < 2048) zi[i] = 0ull;
  } else if (b <= 1230) {
    int gi = (b - 1033) * 256 + t;
    if (gi >= 50688) return;
    const float* src; int off, NSs, OC, mode;
    if (gi < 4608)       { src = ew;    off = 0;     NSs = 3; OC = 16; mode = 0; }
    else if (gi < 12288) { src = p1c1w; off = 4608;  NSs = 5; OC = 16; mode = 1; }
    else if (gi < 27648) { src = p1c2w; off = 12288; NSs = 5; OC = 32; mode = 1; }
    else if (gi < 35328) { src = p2c1w; off = 27648; NSs = 5; OC = 16; mode = 1; }
    else                 { src = p2c2w; off = 35328; NSs = 5; OC = 32; mode = 1; }
    int i = gi - off;
    int ic = i & 7;
    int r = i >> 3;
    int oc = r % OC; r /= OC;
    int kc = r & 3; r >>= 2;
    int s = r % NSs;
    int sp = r / NSs;
    int tap, icf, IC;
    if (mode == 0) { tap = s * 4 + kc; icf = ic; IC = 8; }
    else           { tap = s * 2 + (kc >> 1); icf = (kc & 1) * 8 + ic; IC = 16; }
    float w = 0.f;
    if (tap < 9) {
      int ky = tap / 3, kx = tap - ky * 3;
      w = src[((oc * IC + icf) * 3 + ky) * 3 + kx];
    }
    unsigned short h[3];
    split3<3>(w, h);
    wt[gi] = h[sp];
  } else {
    int blk = b - 1231;
    if (blk < 4096) {
      size_t i = ((size_t)blk * 256 + t) * 4;
      f32x4 v = *reinterpret_cast<const f32x4*>(p1lw + i);
      ushort4v a, b2;
      #pragma unroll
      for (int j = 0; j < 4; ++j) {
        unsigned short h[3];
        split3<2>(v[j], h);
        a[j] = h[0]; b2[j] = h[1];
      }
      *reinterpret_cast<ushort4v*>(w0 + i) = a;
      *reinterpret_cast<ushort4v*>(w1 + i) = b2;
    } else {
      size_t i = ((size_t)(blk - 4096) * 256 + t) * 4;
      f32x4 v = *reinterpret_cast<const f32x4*>(p2lw + i);
      ushort4v a, b2, c;
      #pragma unroll
      for (int j = 0; j < 4; ++j) {
        unsigned short h[3];
        split3<3>(v[j], h);
        a[j] = h[0]; b2[j] = h[1]; c[j] = h[2];
      }
      *reinterpret_cast<ushort4v*>(u0 + i) = a;
      *reinterpret_cast<ushort4v*>(u1 + i) = b2;
      *reinterpret_cast<ushort4v*>(u2 + i) = c;
    }
  }
}

// ---------------------------------------------------------------------------
// K1: row-normalize (rows x 512) + bias, emit 2-3 bf16 splits; optionally
// re-zero the source buffer for atomic reuse.
// ---------------------------------------------------------------------------
__global__ __launch_bounds__(256) void reduce_norm_kernel(
    const float* __restrict__ pre, const float* __restrict__ bias, float eps,
    unsigned short* __restrict__ o0, unsigned short* __restrict__ o1,
    unsigned short* __restrict__ o2, float* __restrict__ zero_dst)
{
  int row = blockIdx.x, t = threadIdx.x;
  size_t base = (size_t)row * 512 + t * 2;
  float2 v = *reinterpret_cast<const float2*>(pre + base);
  float ax = v.x + bias[t * 2], ay = v.y + bias[t * 2 + 1];
  float ss = ax * ax + ay * ay;
  #pragma unroll
  for (int m = 32; m >= 1; m >>= 1) ss += __shfl_xor(ss, m, 64);
  __shared__ float wsum[4];
  int lane = t & 63, wid = t >> 6;
  if (lane == 0) wsum[wid] = ss;
  __syncthreads();
  float tot = wsum[0] + wsum[1] + wsum[2] + wsum[3];
  float inv = 1.0f / (sqrtf(tot) + eps);
  float a = ax * inv, b2 = ay * inv;
  unsigned short ha[3], hb[3];
  split3<3>(a, ha); split3<3>(b2, hb);
  o0[base] = ha[0]; o0[base + 1] = hb[0];
  o1[base] = ha[1]; o1[base + 1] = hb[1];
  if (o2) { o2[base] = ha[2]; o2[base + 1] = hb[2]; }
  if (zero_dst) {
    float2 z = {0.f, 0.f};
    *reinterpret_cast<float2*>(zero_dst + base) = z;
  }
}

// ---------------------------------------------------------------------------
// K3: fused MFMA tower (verified rounds 3-6).
// ---------------------------------------------------------------------------
template<int NS>
__global__ __launch_bounds__(256) void tower_mfma_kernel(
    const int* __restrict__ sIdx, const int* __restrict__ spIdx,
    const float* __restrict__ tblf,
    const unsigned short* __restrict__ wtE,
    const unsigned short* __restrict__ wt1,
    const unsigned short* __restrict__ wt2,
    const float* __restrict__ eb, const float* __restrict__ c1b,
    const float* __restrict__ c2b,
    unsigned short* __restrict__ a0, unsigned short* __restrict__ a1,
    unsigned short* __restrict__ a2, int delta)
{
  __shared__ float tbl[112];
  __shared__ ushort8 G[NS][324];      // [cell][8ch]
  __shared__ ushort8 Abuf[NS][648];   // [cell][16ch] swizzled
  __shared__ ushort8 Bbuf[NS][648];

  const int b = blockIdx.x, t = threadIdx.x;
  const int lane = t & 63, wv = t >> 6;
  const int fr = lane & 15, kc = lane >> 4;

  if (t < 112) tbl[t] = tblf[t];
  // zero only the 68-cell halo ring (interiors are fully overwritten)
  if (t < 68) {
    int c;
    if (t < 18)      c = t;
    else if (t < 36) c = 306 + (t - 18);
    else if (t < 52) c = 18 * (t - 35);
    else             c = 18 * (t - 51) + 17;
    ushort8 z8 = {0, 0, 0, 0, 0, 0, 0, 0};
    #pragma unroll
    for (int sp = 0; sp < NS; ++sp) {
      G[sp][c] = z8;
      ((ushort8*)&Abuf[sp][0])[conv_a16(c, 0)] = z8;
      ((ushort8*)&Abuf[sp][0])[conv_a16(c, 1)] = z8;
      ((ushort8*)&Bbuf[sp][0])[conv_a16(c, 0)] = z8;
      ((ushort8*)&Bbuf[sp][0])[conv_a16(c, 1)] = z8;
    }
  }
  __syncthreads();

  // ---- gather + split -> G ----
  {
    const int y = t >> 4, x = t & 15;
    const int cell = (y + 1) * 18 + (x + 1);
    int sv = sIdx[(size_t)b * 256 + t];
    float v[8];
    if (delta) {
      int spv = spIdx[(size_t)b * 256 + t];
      #pragma unroll
      for (int c = 0; c < 8; ++c) v[c] = tbl[spv * 8 + c] - tbl[sv * 8 + c];
    } else {
      #pragma unroll
      for (int c = 0; c < 8; ++c) v[c] = tbl[sv * 8 + c];
    }
    ushort8 h0, h1, h2;
    #pragma unroll
    for (int c = 0; c < 8; ++c) {
      unsigned short q[3];
      split3<NS>(v[c], q);
      h0[c] = q[0]; h1[c] = q[1];
      if constexpr (NS == 3) h2[c] = q[2];
    }
    G[0][cell] = h0; G[1][cell] = h1;
    if constexpr (NS == 3) G[2][cell] = h2;
  }
  __syncthreads();

  // ---- embed conv 8->16 (no relu; bias only for tower1) -> Abuf ----
  {
    float bias = 0.f;
    if (!delta) bias = eb[fr];
    f32x4 acc[4];
    #pragma unroll
    for (int j = 0; j < 4; ++j) acc[j] = (f32x4)0.f;
    #pragma unroll
    for (int s = 0; s < 3; ++s) {
      bf16x8 bw[NS];
      #pragma unroll
      for (int sp = 0; sp < NS; ++sp)
        bw[sp] = __builtin_bit_cast(bf16x8, *reinterpret_cast<const ushort8*>(
            wtE + (size_t)(((sp * 3 + s) * 4 + kc) * 16 + fr) * 8));
      int tap = s * 4 + kc; if (tap > 8) tap = 8;
      const int dy = tap / 3, dx = tap - dy * 3;
      const int cb = dy * 18 + fr + dx;
      #pragma unroll
      for (int j = 0; j < 4; ++j) {
        const int cell = cb + (wv * 4 + j) * 18;
        bf16x8 av[NS];
        #pragma unroll
        for (int sp = 0; sp < NS; ++sp)
          av[sp] = __builtin_bit_cast(bf16x8, G[sp][cell]);
        acc[j] = mfma_prod<NS>(av, bw, acc[j]);
      }
    }
    #pragma unroll
    for (int j = 0; j < 4; ++j) {
      const int y = wv * 4 + j;
      #pragma unroll
      for (int q = 0; q < 4; ++q) {
        const int x = kc * 4 + q;
        const int cell = (y + 1) * 18 + (x + 1);
        const int a16 = conv_a16(cell, fr >> 3);
        unsigned short hh[3];
        split3<NS>(acc[j][q] + bias, hh);
        #pragma unroll
        for (int sp = 0; sp < NS; ++sp)
          ((unsigned short*)&Abuf[sp][0])[a16 * 8 + (fr & 7)] = hh[sp];
      }
    }
  }
  __syncthreads();

  // ---- conv1 16->16, relu -> Bbuf ----
  {
    const float bias = c1b[fr];
    f32x4 acc[4];
    #pragma unroll
    for (int j = 0; j < 4; ++j) acc[j] = (f32x4)0.f;
    #pragma unroll
    for (int s = 0; s < 5; ++s) {
      bf16x8 bw[NS];
      #pragma unroll
      for (int sp = 0; sp < NS; ++sp)
        bw[sp] = __builtin_bit_cast(bf16x8, *reinterpret_cast<const ushort8*>(
            wt1 + (size_t)(((sp * 5 + s) * 4 + kc) * 16 + fr) * 8));
      int tap = s * 2 + (kc >> 1); if (tap > 8) tap = 8;
      const int dy = tap / 3, dx = tap - dy * 3;
      const int half = kc & 1;
      const int cb = dy * 18 + fr + dx;
      #pragma unroll
      for (int j = 0; j < 4; ++j) {
        const int cell = cb + (wv * 4 + j) * 18;
        const int a16 = conv_a16(cell, half);
        bf16x8 av[NS];
        #pragma unroll
        for (int sp = 0; sp < NS; ++sp)
          av[sp] = __builtin_bit_cast(bf16x8, *reinterpret_cast<const ushort8*>(
              (const unsigned short*)&Abuf[sp][0] + a16 * 8));
        acc[j] = mfma_prod<NS>(av, bw, acc[j]);
      }
    }
    #pragma unroll
    for (int j = 0; j < 4; ++j) {
      const int y = wv * 4 + j;
      #pragma unroll
      for (int q = 0; q < 4; ++q) {
        const int x = kc * 4 + q;
        const int cell = (y + 1) * 18 + (x + 1);
        const int a16 = conv_a16(cell, fr >> 3);
        unsigned short hh[3];
        split3<NS>(fmaxf(acc[j][q] + bias, 0.f), hh);
        #pragma unroll
        for (int sp = 0; sp < NS; ++sp)
          ((unsigned short*)&Bbuf[sp][0])[a16 * 8 + (fr & 7)] = hh[sp];
      }
    }
  }
  __syncthreads();

  // ---- conv2 16->32, relu -> global act splits ----
  {
    const float bias0 = c2b[fr], bias1 = c2b[16 + fr];
    f32x4 acc0[4], acc1[4];
    #pragma unroll
    for (int j = 0; j < 4; ++j) { acc0[j] = (f32x4)0.f; acc1[j] = (f32x4)0.f; }
    #pragma unroll
    for (int s = 0; s < 5; ++s) {
      bf16x8 bw0[NS], bw1[NS];
      #pragma unroll
      for (int sp = 0; sp < NS; ++sp) {
        size_t base = (size_t)(((sp * 5 + s) * 4 + kc) * 32) * 8;
        bw0[sp] = __builtin_bit_cast(bf16x8,
            *reinterpret_cast<const ushort8*>(wt2 + base + (size_t)fr * 8));
        bw1[sp] = __builtin_bit_cast(bf16x8,
            *reinterpret_cast<const ushort8*>(wt2 + base + (size_t)(16 + fr) * 8));
      }
      int tap = s * 2 + (kc >> 1); if (tap > 8) tap = 8;
      const int dy = tap / 3, dx = tap - dy * 3;
      const int half = kc & 1;
      const int cb = dy * 18 + fr + dx;
      #pragma unroll
      for (int j = 0; j < 4; ++j) {
        const int cell = cb + (wv * 4 + j) * 18;
        const int a16 = conv_a16(cell, half);
        bf16x8 av[NS];
        #pragma unroll
        for (int sp = 0; sp < NS; ++sp)
          av[sp] = __builtin_bit_cast(bf16x8, *reinterpret_cast<const ushort8*>(
              (const unsigned short*)&Bbuf[sp][0] + a16 * 8));
        acc0[j] = mfma_prod<NS>(av, bw0, acc0[j]);
        acc1[j] = mfma_prod<NS>(av, bw1, acc1[j]);
      }
    }
    #pragma unroll
    for (int j = 0; j < 4; ++j) {
      const int y = wv * 4 + j;
      ushort4v g0[2], g1[2], g2[2];
      #pragma unroll
      for (int q = 0; q < 4; ++q) {
        unsigned short hh[3];
        split3<NS>(fmaxf(acc0[j][q] + bias0, 0.f), hh);
        g0[0][q] = hh[0]; g1[0][q] = hh[1]; if constexpr (NS == 3) g2[0][q] = hh[2];
        split3<NS>(fmaxf(acc1[j][q] + bias1, 0.f), hh);
        g0[1][q] = hh[0]; g1[1][q] = hh[1]; if constexpr (NS == 3) g2[1][q] = hh[2];
      }
      size_t base0 = (size_t)b * 8192 + (size_t)fr * 256 + y * 16 + kc * 4;
      size_t base1 = base0 + 16 * 256;
      *reinterpret_cast<ushort4v*>(a0 + base0) = g0[0];
      *reinterpret_cast<ushort4v*>(a0 + base1) = g0[1];
      *reinterpret_cast<ushort4v*>(a1 + base0) = g1[0];
      *reinterpret_cast<ushort4v*>(a1 + base1) = g1[1];
      if constexpr (NS == 3) {
        *reinterpret_cast<ushort4v*>(a2 + base0) = g2[0];
        *reinterpret_cast<ushort4v*>(a2 + base1) = g2[1];
      }
    }
  }
}

// ---------------------------------------------------------------------------
// K4: split-bf16 MFMA GEMM, C = A @ B^T.  128x128 tile, BK=32, 4 waves.
//   A and B: pre-split NS tiles via global_load_lds (pre-swizzled source).
//   Pipeline (single-buffer, 2 barriers/K-step):
//     stage(0); loop { barrier[vm drain] -> read ALL frags -> barrier
//                      -> stage(kt+1) -> MFMAs }
//   so next-tile load latency hides under the 48/96-MFMA block.
//   EPI: 0 = atomicAdd into C (K-split reduction)
//        2 = final write: gather B row from packed zi keys, * exp(scale)
//        3 = score-argmax: per-row packed-key atomicMax into zout (no C)
// ---------------------------------------------------------------------------
template<int NS, int EPI>
__global__ __launch_bounds__(256) void mfma_gemm_kernel(
    const unsigned short* __restrict__ A0, const unsigned short* __restrict__ A1,
    const unsigned short* __restrict__ A2,
    const unsigned short* __restrict__ B0, const unsigned short* __restrict__ B1,
    const unsigned short* __restrict__ B2,
    const unsigned long long* __restrict__ gkey,
    unsigned long long* __restrict__ zout,
    const float* __restrict__ scale_p,
    float* __restrict__ C, int M, int N, int K, int Ksub)
{
  __shared__ unsigned short ldsA[NS][4096];
  __shared__ unsigned short ldsB[NS][4096];

  const int t = threadIdx.x;
  const int lane = t & 63, wv = t >> 6;
  const int m0 = blockIdx.x * 128, n0 = blockIdx.y * 128;
  const long kbase = (long)blockIdx.z * Ksub;
  const int NT = Ksub >> 5;

  const int st_row = lane >> 2;
  const int st_cb = (lane & 3) * 16;
  int srow[2];
  long bgrow[2];
  #pragma unroll
  for (int r = 0; r < 2; ++r) {
    srow[r] = (wv + 4 * r) * 16 + st_row;
    long g = n0 + srow[r];
    if constexpr (EPI == 2)
      g = 511 - (long)(unsigned)(gkey[n0 + srow[r]] & 0xFFFFFFFFull);
    bgrow[r] = g;
  }

  const int wr = wv >> 1, wc = wv & 1;
  const int fr = lane & 15, kc = lane >> 4;

  f32x4 acc[4][4];
  #pragma unroll
  for (int mi = 0; mi < 4; ++mi)
    #pragma unroll
    for (int ni = 0; ni < 4; ++ni) acc[mi][ni] = (f32x4)0.f;

  const unsigned short* Asp[3] = {A0, A1, A2};
  const unsigned short* Bsp[3] = {B0, B1, B2};

  auto stage = [&](int kt) {
    const long k0 = kbase + (long)kt * 32;
    #pragma unroll
    for (int sp = 0; sp < NS; ++sp)
      #pragma unroll
      for (int r = 0; r < 2; ++r) {
        int row = srow[r];
        int c = st_cb ^ (((row >> 1) & 3) << 4);
        gload_lds16(Asp[sp] + (size_t)(m0 + row) * K + k0 + (c >> 1),
                    &ldsA[sp][(wv + 4 * r) * 512]);
        gload_lds16(Bsp[sp] + (size_t)bgrow[r] * K + k0 + (c >> 1),
                    &ldsB[sp][(wv + 4 * r) * 512]);
      }
  };

  stage(0);
  for (int kt = 0; kt < NT; ++kt) {
    __syncthreads();   // drains vmcnt: tile kt resident in LDS

    // ---- read ALL fragments into registers ----
    bf16x8 af[NS][4], bf[NS][4];
    #pragma unroll
    for (int sp = 0; sp < NS; ++sp) {
      #pragma unroll
      for (int mi = 0; mi < 4; ++mi) {
        int row = wr * 64 + mi * 16 + fr;
        int cb = (kc * 16) ^ (((row >> 1) & 3) << 4);
        af[sp][mi] = __builtin_bit_cast(bf16x8,
            *reinterpret_cast<const ushort8*>(&ldsA[sp][row * 32 + (cb >> 1)]));
      }
      #pragma unroll
      for (int ni = 0; ni < 4; ++ni) {
        int row = wc * 64 + ni * 16 + fr;
        int cb = (kc * 16) ^ (((row >> 1) & 3) << 4);
        bf[sp][ni] = __builtin_bit_cast(bf16x8,
            *reinterpret_cast<const ushort8*>(&ldsB[sp][row * 32 + (cb >> 1)]));
      }
    }
    __syncthreads();   // all waves done reading LDS -> safe to overwrite

    if (kt + 1 < NT) stage(kt + 1);   // loads fly under the MFMA block

    #pragma unroll
    for (int mi = 0; mi < 4; ++mi)
      #pragma unroll
      for (int ni = 0; ni < 4; ++ni) {
        f32x4 c = acc[mi][ni];
        c = MFMA16(af[0][mi], bf[0][ni], c);
        c = MFMA16(af[0][mi], bf[1][ni], c);
        c = MFMA16(af[1][mi], bf[0][ni], c);
        if constexpr (NS == 3) {
          c = MFMA16(af[1][mi], bf[1][ni], c);
          c = MFMA16(af[0][mi], bf[2][ni], c);
          c = MFMA16(af[2][mi], bf[0][ni], c);
        }
        acc[mi][ni] = c;
      }
  }

  // epilogue: C/D layout col=lane&15, row=(lane>>4)*4+q
  if constexpr (EPI == 0) {
    #pragma unroll
    for (int mi = 0; mi < 4; ++mi)
      #pragma unroll
      for (int ni = 0; ni < 4; ++ni) {
        int col = n0 + wc * 64 + ni * 16 + fr;
        #pragma unroll
        for (int q = 0; q < 4; ++q) {
          int row = m0 + wr * 64 + mi * 16 + kc * 4 + q;
          atomicAdd(&C[(size_t)row * N + col], acc[mi][ni][q]);
        }
      }
  } else if constexpr (EPI == 2) {
    float scl = expf(scale_p[0]);
    #pragma unroll
    for (int mi = 0; mi < 4; ++mi)
      #pragma unroll
      for (int ni = 0; ni < 4; ++ni) {
        int col = n0 + wc * 64 + ni * 16 + fr;
        #pragma unroll
        for (int q = 0; q < 4; ++q) {
          int row = m0 + wr * 64 + mi * 16 + kc * 4 + q;
          C[(size_t)row * N + col] = acc[mi][ni][q] * scl;
        }
      }
  } else {  // EPI == 3: fused argmax (full K per block)
    #pragma unroll
    for (int mi = 0; mi < 4; ++mi)
      #pragma unroll
      for (int q = 0; q < 4; ++q) {
        int row = m0 + wr * 64 + mi * 16 + kc * 4 + q;
        unsigned long long best = 0ull;
        #pragma unroll
        for (int ni = 0; ni < 4; ++ni) {
          int col = n0 + wc * 64 + ni * 16 + fr;
          unsigned long long k2 = score_key(acc[mi][ni][q], col);
          best = (k2 > best) ? k2 : best;
        }
        #pragma unroll
        for (int m2 = 1; m2 < 16; m2 <<= 1) {
          unsigned long long o = shfl_xor_u64(best, m2);
          best = (o > best) ? o : best;
        }
        if (fr == 0) atomicMax(zout + row, best);
      }
  }
}

// ---------------------------------------------------------------------------
// launch
// ---------------------------------------------------------------------------
extern "C" void kernel_launch(void* const* d_in, const int* in_sizes, int n_in,
                              void* d_out, int out_size, void* d_ws, size_t ws_size,
                              hipStream_t stream)
{
  const int*   s      = (const int*)  d_in[0];
  const int*   sprime = (const int*)  d_in[1];
  const float* se     = (const float*)d_in[2];
  const float* ew     = (const float*)d_in[3];
  const float* eb     = (const float*)d_in[4];
  const float* p1c1w  = (const float*)d_in[5];
  const float* p1c1b  = (const float*)d_in[6];
  const float* p1c2w  = (const float*)d_in[7];
  const float* p1c2b  = (const float*)d_in[8];
  const float* p1lw   = (const float*)d_in[9];
  const float* p1lb   = (const float*)d_in[10];
  const float* p2c1w  = (const float*)d_in[11];
  const float* p2c1b  = (const float*)d_in[12];
  const float* p2c2w  = (const float*)d_in[13];
  const float* p2c2b  = (const float*)d_in[14];
  const float* p2lw   = (const float*)d_in[15];
  const float* p2lb   = (const float*)d_in[16];
  const float* zv     = (const float*)d_in[17];
  const float* scale  = (const float*)d_in[18];
  float* out = (float*)d_out;

  // ---- workspace (peak ~136 MB) ----
  char* w = (char*)d_ws;
  size_t off = 0;
  auto alloc = [&](size_t bytes) -> char* {
    char* p = w + off;
    off += (bytes + 255) & ~(size_t)255;
    return p;
  };
  float* tblf = (float*)alloc(112 * 4);
  unsigned short* zn0 = (unsigned short*)alloc((size_t)512 * 512 * 2);
  unsigned short* zn1 = (unsigned short*)alloc((size_t)512 * 512 * 2);
  unsigned short* zn2 = (unsigned short*)alloc((size_t)512 * 512 * 2);
  unsigned short* e10 = (unsigned short*)alloc((size_t)2048 * 512 * 2);
  unsigned short* e11 = (unsigned short*)alloc((size_t)2048 * 512 * 2);
  unsigned short* e20 = (unsigned short*)alloc((size_t)2048 * 512 * 2);
  unsigned short* e21 = (unsigned short*)alloc((size_t)2048 * 512 * 2);
  unsigned short* e22 = (unsigned short*)alloc((size_t)2048 * 512 * 2);
  float* epre = (float*)alloc((size_t)2048 * 512 * 4);
  unsigned long long* zi = (unsigned long long*)alloc(2048 * 8);
  unsigned short* wt = (unsigned short*)alloc((size_t)50688 * 2);
  unsigned short* act0 = (unsigned short*)alloc((size_t)2048 * 8192 * 2);
  unsigned short* act1 = (unsigned short*)alloc((size_t)2048 * 8192 * 2);
  unsigned short* act2 = (unsigned short*)alloc((size_t)2048 * 8192 * 2);
  unsigned short* u0 = (unsigned short*)alloc((size_t)512 * 8192 * 2);
  unsigned short* u1 = (unsigned short*)alloc((size_t)512 * 8192 * 2);
  unsigned short* u2 = (unsigned short*)alloc((size_t)512 * 8192 * 2);
  // p1 linear-weight splits alias act2 (32 MB >= 2 x 8 MB): tower1 is NS=2
  // (never writes act2); tower2 overwrites act2 only after GEMM1 completes.
  unsigned short* w0 = act2;
  unsigned short* w1 = act2 + (size_t)512 * 8192;

  unsigned short* wtE  = wt;
  unsigned short* wt1a = wt + 4608;
  unsigned short* wt2a = wt + 12288;
  unsigned short* wt1b = wt + 27648;
  unsigned short* wt2b = wt + 35328;

  // ---- one fused prep dispatch ----
  prep_all_kernel<<<9423, 256, 0, stream>>>(
      se, tblf, zv, zn0, zn1, zn2, epre, zi,
      ew, p1c1w, p1c2w, p2c1w, p2c2w, wt,
      p1lw, p2lw, w0, w1, u0, u1, u2);

  // ---- tower 1 (2-way split) -> act0/1 ; linear (KSPLIT=8) ; norm ----
  tower_mfma_kernel<2><<<2048, 256, 0, stream>>>(
      s, sprime, tblf, wtE, wt1a, wt2a, eb, p1c1b, p1c2b, act0, act1, act2, 0);
  mfma_gemm_kernel<2, 0><<<dim3(16, 4, 8), 256, 0, stream>>>(
      act0, act1, nullptr, w0, w1, nullptr, nullptr, nullptr,
      nullptr, epre, 2048, 512, 8192, 1024);
  reduce_norm_kernel<<<2048, 256, 0, stream>>>(epre, p1lb, 1e-4f,
                                               e10, e11, nullptr, epre);

  // ---- tower 2 (3-way split, argmax-critical) -> act0/1/2 ; linear ; norm --
  tower_mfma_kernel<3><<<2048, 256, 0, stream>>>(
      s, sprime, tblf, wtE, wt1b, wt2b, eb, p2c1b, p2c2b, act0, act1, act2, 1);
  mfma_gemm_kernel<3, 0><<<dim3(16, 4, 8), 256, 0, stream>>>(
      act0, act1, act2, u0, u1, u2, nullptr, nullptr,
      nullptr, epre, 2048, 512, 8192, 1024);
  reduce_norm_kernel<<<2048, 256, 0, stream>>>(epre, p2lb, 1e-4f,
                                               e20, e21, e22, nullptr);

  // ---- fused score+argmax (full-K blocks) -> final gathered GEMM ----
  mfma_gemm_kernel<3, 3><<<dim3(16, 4, 1), 256, 0, stream>>>(
      e20, e21, e22, zn0, zn1, zn2, nullptr, zi, nullptr,
      nullptr, 2048, 512, 512, 512);
  mfma_gemm_kernel<2, 2><<<dim3(16, 16, 1), 256, 0, stream>>>(
      e10, e11, nullptr, zn0, zn1, nullptr, zi, nullptr, scale,
      out, 2048, 2048, 512, 512);
}